// Round 1
// baseline (176.897 us; speedup 1.0000x reference)
//
#include <hip/hip_runtime.h>
#include <stdint.h>
#include <stddef.h>

#define GLOBAL_AS __attribute__((address_space(1)))
#define LDS_AS    __attribute__((address_space(3)))

typedef __bf16 bf16x8 __attribute__((ext_vector_type(8)));
typedef float  f32x4  __attribute__((ext_vector_type(4)));

// Problem constants: x(8,256,64,64) fp32, W(128,256,4,4), bias(128,4,4), stride 2, out(8,128,130,130)
constexpr int NB = 8, CI = 256, H_ = 64, W_ = 64, CO = 128;
constexpr int OH = 130, OW = 130;
constexpr int PU = 65;    // per-parity output extent (0..64)
constexpr int PAD = 66;   // padded x extent: index p = (u-a)+1 in [0,66), borders zero

// Workspace layout
constexpr size_t XPAD_ELEMS = (size_t)NB * PAD * PAD * CI;       // bf16 elems
constexpr size_t XPAD_BYTES = XPAD_ELEMS * 2;                    // 17,842,176
constexpr size_t SLACK      = 256 * 1024;                        // OOB-read guard (zeroed)
constexpr size_t WT_OFF     = XPAD_BYTES + SLACK;                // W_t offset in ws
constexpr size_t WT_ELEMS   = (size_t)16 * CO * CI;              // 524,288 bf16

__device__ __forceinline__ void gload_lds16(const void* g, void* l) {
  __builtin_amdgcn_global_load_lds((GLOBAL_AS void*)g, (LDS_AS void*)l, 16, 0, 0);
}

// ---- prep 1: x (b,i,h,w) fp32 -> x_padT[b][h+1][w+1][i] bf16 (zero borders via memset) ----
__global__ void prep_x(const float* __restrict__ x, __bf16* __restrict__ xp) {
  __shared__ float tile[64][65];
  const int ib = blockIdx.x;           // i-block of 64
  const int h  = blockIdx.y;
  const int bat = blockIdx.z;
  const int t  = threadIdx.x;
  const int i0 = ib * 64;
  const float* src = x + (((size_t)(bat * CI + i0)) * H_ + h) * W_;
#pragma unroll
  for (int p = 0; p < 16; ++p) {
    int ii = p * 4 + (t >> 6);
    int ww = t & 63;
    tile[ii][ww] = src[(size_t)ii * H_ * W_ + ww];   // 256B coalesced per wave
  }
  __syncthreads();
  __bf16* dst = xp + ((size_t)(bat * PAD + h + 1) * PAD + 1) * CI + i0;
#pragma unroll
  for (int p = 0; p < 16; ++p) {
    int ww = p * 4 + (t >> 6);
    int il = t & 63;
    dst[(size_t)ww * CI + il] = (__bf16)tile[il][ww]; // 128B coalesced per wave
  }
}

// ---- prep 2: W (o,i,ky,kx) fp32 -> W_t[tap=ky*4+kx][o][i] bf16 ----
__global__ void prep_w(const float* __restrict__ w, __bf16* __restrict__ wt) {
  int tid = blockIdx.x * 256 + threadIdx.x;          // [0, 524288)
  int i   = tid & 255;
  int o   = (tid >> 8) & 127;
  int tap = tid >> 15;
  wt[tid] = (__bf16)w[(size_t)(o * CI + i) * 16 + tap];
}

// ---- main: per-parity 4-tap GEMM, M=128(o) x N=128(8u x 16v) x K=1024 ----
__global__ __launch_bounds__(256) void deconv_mfma(
    const __bf16* __restrict__ xp, const __bf16* __restrict__ wt,
    const float* __restrict__ bias, float* __restrict__ out) {
  // grid: wg = ((pid*8 + b)*9 + ut)*5 + vt ; 4*8*9*5 = 1440
  const int wg  = blockIdx.x;
  const int vt  = wg % 5;
  const int ut  = (wg / 5) % 9;
  const int bat = (wg / 45) % 8;
  const int pid = wg / 360;
  const int py = pid >> 1, px = pid & 1;
  const int u0 = ut * 8, v0 = vt * 16;

  __shared__ alignas(16) __bf16 lds[2][8192];  // per buf: A elems [0,4096) (128o x 32k), B elems [4096,8192) (128n x 32k)

  const int t    = threadIdx.x;
  const int wid  = t >> 6, lane = t & 63;
  const int lr   = lane & 15, kg = lane >> 4;
  const int wr   = wid >> 1, wc = wid & 1;

  // ---- staging invariants (thread t covers phys chunks q=t and q=t+256 of each tile) ----
  const int kst = (t & 3) ^ ((t >> 3) & 3);    // logical k-group for this phys slot (XOR swizzle, involution)
  const int m0  = t >> 2;                       // row (o for A, n for B) of chunk q=t
  const int du0 = m0 >> 4, dv0 = m0 & 15;       // B pixel decode (n = du*16+dv)

  const __bf16* srcA0 = wt + (size_t)m0 * CI + (size_t)kst * 8;           // + tapW*CO*CI + ic
  const __bf16* srcB00 = xp + ((size_t)(bat * PAD + u0 + 1) * PAD + (v0 + 1)) * CI
                         + (size_t)du0 * PAD * CI + (size_t)dv0 * CI + (size_t)kst * 8; // + ic - (a*PAD+c)*CI

  __bf16* ldsA0[2] = { &lds[0][0] + wid * 512, &lds[1][0] + wid * 512 };
  __bf16* ldsB0[2] = { &lds[0][4096] + wid * 512, &lds[1][4096] + wid * 512 };

  // ---- fragment read offsets (within-buffer elems), swizzled to match staging ----
  const int swz = (lr >> 1) & 3;
  int offA[4], offB[4];
#pragma unroll
  for (int mt = 0; mt < 4; ++mt) {
    int m = wr * 64 + mt * 16 + lr;
    offA[mt] = m * 32 + ((kg ^ swz) * 8);
  }
#pragma unroll
  for (int nt = 0; nt < 4; ++nt) {
    int n = wc * 64 + nt * 16 + lr;
    offB[nt] = n * 32 + ((kg ^ swz) * 8);
  }

  f32x4 acc[4][4] = {};

  auto stage = [&](int buf, int s) {
    const int tap = s >> 3;             // 0..3 : (a,c)
    const int ic  = (s & 7) * 32;       // i-chunk
    const int a = tap >> 1, c = tap & 1;
    const int tapW = (py + 2 * a) * 4 + (px + 2 * c);
    const __bf16* sa = srcA0 + (size_t)tapW * CO * CI + ic;
    const __bf16* sb = srcB00 - (size_t)(a * PAD + c) * CI + ic;
    gload_lds16(sa,                          ldsA0[buf]);
    gload_lds16(sa + (size_t)64 * CI,        ldsA0[buf] + 2048);
    gload_lds16(sb,                          ldsB0[buf]);
    gload_lds16(sb + (size_t)4 * PAD * CI,   ldsB0[buf] + 2048);
  };

  stage(0, 0);
  __syncthreads();           // drains vmcnt before first reads
  int cur = 0;
  for (int s = 0; s < 32; ++s) {
    if (s < 31) stage(cur ^ 1, s + 1);
    const __bf16* ab = &lds[cur][0];
    const __bf16* bb = &lds[cur][4096];
    bf16x8 af[4], bfr[4];
#pragma unroll
    for (int mt = 0; mt < 4; ++mt) af[mt]  = *(const bf16x8*)(ab + offA[mt]);
#pragma unroll
    for (int nt = 0; nt < 4; ++nt) bfr[nt] = *(const bf16x8*)(bb + offB[nt]);
#pragma unroll
    for (int mt = 0; mt < 4; ++mt)
#pragma unroll
      for (int nt = 0; nt < 4; ++nt)
        acc[mt][nt] = __builtin_amdgcn_mfma_f32_16x16x32_bf16(af[mt], bfr[nt], acc[mt][nt], 0, 0, 0);
    __syncthreads();
    cur ^= 1;
  }

  // ---- epilogue: bias with per-tap validity, write fp32 ----
  const int dv = lr, v = v0 + dv;
  const bool vok = (v < PU);
  const bool c0 = (v <= 63), c1 = (v >= 1);
  const int ox = 2 * v + px;
#pragma unroll
  for (int mt = 0; mt < 4; ++mt) {
#pragma unroll
    for (int r = 0; r < 4; ++r) {
      const int o = wr * 64 + mt * 16 + kg * 4 + r;   // D row = (lane>>4)*4 + r  [m89-verified]
      const float* bp = bias + (size_t)o * 16;
      const float b00 = bp[py * 4 + px];
      const float b01 = bp[py * 4 + px + 2];
      const float b10 = bp[(py + 2) * 4 + px];
      const float b11 = bp[(py + 2) * 4 + px + 2];
      const size_t orow = (size_t)(bat * CO + o) * (OH * OW);
#pragma unroll
      for (int nt = 0; nt < 4; ++nt) {
        const int du = wc * 4 + nt;
        const int u = u0 + du;
        if (u < PU && vok) {
          const bool a0 = (u <= 63), a1 = (u >= 1);
          float bs = (a0 && c0 ? b00 : 0.f) + (a0 && c1 ? b01 : 0.f)
                   + (a1 && c0 ? b10 : 0.f) + (a1 && c1 ? b11 : 0.f);
          const int oy = 2 * u + py;
          out[orow + (size_t)oy * OW + ox] = acc[mt][nt][r] + bs;
        }
      }
    }
  }
}

extern "C" void kernel_launch(void* const* d_in, const int* in_sizes, int n_in,
                              void* d_out, int out_size, void* d_ws, size_t ws_size,
                              hipStream_t stream) {
  const float* x    = (const float*)d_in[0];
  const float* w    = (const float*)d_in[1];
  const float* bias = (const float*)d_in[2];
  float* out = (float*)d_out;
  char* ws = (char*)d_ws;
  __bf16* xpad = (__bf16*)ws;
  __bf16* wt   = (__bf16*)(ws + WT_OFF);

  // zero x_padT + slack (borders/overreads must be 0); re-run every launch (ws is re-poisoned)
  hipMemsetAsync(ws, 0, WT_OFF, stream);
  prep_x<<<dim3(4, 64, 8), 256, 0, stream>>>(x, xpad);
  prep_w<<<dim3(2048), 256, 0, stream>>>(w, wt);
  deconv_mfma<<<dim3(1440), 256, 0, stream>>>(xpad, wt, bias, out);
}